// Round 1
// baseline (1561.291 us; speedup 1.0000x reference)
//
#include <hip/hip_runtime.h>

#define NN 50000
#define NE 800000
#define NG 256

__global__ void k_init_deg(float* deg, int n) {
    int i = blockIdx.x * blockDim.x + threadIdx.x;
    if (i < n) deg[i] = 1.0f;   // self-loop weight
}

__global__ void k_deg_accum(const int* __restrict__ col, const float* __restrict__ w,
                            float* deg, int e) {
    int i = blockIdx.x * blockDim.x + threadIdx.x;
    if (i < e) atomicAdd(&deg[col[i]], w[i]);
}

__global__ void k_dis(float* deg, int n) {
    int i = blockIdx.x * blockDim.x + threadIdx.x;
    if (i < n) {
        float d = deg[i];
        deg[i] = d > 0.f ? rsqrtf(fmaxf(d, 1e-12f)) : 0.f;  // in-place -> dis
    }
}

__global__ void k_norm(const int* __restrict__ row, const int* __restrict__ col,
                       const float* __restrict__ w, const float* __restrict__ dis,
                       float* __restrict__ norm, int e) {
    int i = blockIdx.x * blockDim.x + threadIdx.x;
    if (i < e) norm[i] = dis[row[i]] * w[i] * dis[col[i]];
}

// m[n,j] = sum_k h[n,k] * W[k,j]
__global__ void k_gemm(const float* __restrict__ h, const float* __restrict__ W,
                       float* __restrict__ m, int n, int din, int dout) {
    int t = blockIdx.x * blockDim.x + threadIdx.x;
    if (t >= n * dout) return;
    int node = t / dout;
    int j = t - node * dout;
    const float* hr = h + (long)node * din;
    float acc = 0.f;
    for (int k = 0; k < din; ++k) acc += hr[k] * W[k * dout + j];
    m[t] = acc;
}

// agg init with self-loop contribution: agg[i,j] = m[i,j] * dis[i]^2
__global__ void k_selfloop(const float* __restrict__ m, const float* __restrict__ dis,
                           float* __restrict__ agg, int n, int dout) {
    int t = blockIdx.x * blockDim.x + threadIdx.x;
    if (t >= n * dout) return;
    int node = t / dout;
    float d = dis[node];
    agg[t] = m[t] * d * d;
}

__global__ void k_scatter(const int* __restrict__ row, const int* __restrict__ col,
                          const float* __restrict__ norm, const float* __restrict__ m,
                          float* agg, int e, int dout) {
    int t = blockIdx.x * blockDim.x + threadIdx.x;
    if (t >= e * dout) return;
    int ed = t / dout;
    int j = t - ed * dout;
    int r = row[ed], c = col[ed];
    atomicAdd(&agg[c * dout + j], m[r * dout + j] * norm[ed]);
}

__global__ void k_zero(float* p, int n) {
    int i = blockIdx.x * blockDim.x + threadIdx.x;
    if (i < n) p[i] = 0.f;
}

// h += bias, optional relu (in place), accumulate per-channel sum/sumsq.
// Requires gridDim.x*blockDim.x % dout == 0 so each thread maps to one channel.
__global__ void k_bias_stats(float* h, const float* __restrict__ b,
                             float* sum, float* sumsq, int n, int dout, int relu) {
    __shared__ float ls[128], lq[128];
    int tid = threadIdx.x;
    if (tid < dout) { ls[tid] = 0.f; lq[tid] = 0.f; }
    __syncthreads();
    int total = n * dout;
    int stride = gridDim.x * blockDim.x;
    float s = 0.f, q = 0.f;
    int j = -1;
    for (int t = blockIdx.x * blockDim.x + tid; t < total; t += stride) {
        int jj = t % dout;   // constant per thread (stride multiple of dout)
        j = jj;
        float v = h[t] + b[jj];
        if (relu) v = fmaxf(v, 0.f);
        h[t] = v;
        s += v;
        q += v * v;
    }
    if (j >= 0) { atomicAdd(&ls[j], s); atomicAdd(&lq[j], q); }
    __syncthreads();
    if (tid < dout) {
        atomicAdd(&sum[tid], ls[tid]);
        atomicAdd(&sumsq[tid], lq[tid]);
    }
}

__global__ void k_bn_finalize(const float* sum, const float* sumsq,
                              const float* __restrict__ g, const float* __restrict__ bt,
                              float* scale, float* shift, int n, int dout) {
    int j = threadIdx.x;
    if (j >= dout) return;
    float mu = sum[j] / n;
    float var = sumsq[j] / n - mu * mu;
    float a = g[j] * rsqrtf(var + 1e-5f);
    scale[j] = a;
    shift[j] = bt[j] - mu * a;
}

__global__ void k_bn_apply(float* h, const float* __restrict__ scale,
                           const float* __restrict__ shift, int n, int dout, int relu) {
    int t = blockIdx.x * blockDim.x + threadIdx.x;
    if (t >= n * dout) return;
    int node = t / dout;
    int j = t - node * dout;
    float v = scale[j] * h[t] + shift[j];
    if (relu) v = fmaxf(v, 0.f);
    h[t] = v;
}

__global__ void k_pool(const float* __restrict__ h, const int* __restrict__ batch,
                       float* pooled, int n, int dout) {
    int t = blockIdx.x * blockDim.x + threadIdx.x;
    if (t >= n * dout) return;
    int node = t / dout;
    int j = t - node * dout;
    atomicAdd(&pooled[batch[node] * dout + j], h[t]);
}

// one block per graph, 64 threads (= 1 wave): fc1 (128->64), relu, fc2 (64->1)
__global__ void k_head(const float* __restrict__ pooled,
                       const float* __restrict__ fc1w, const float* __restrict__ fc1b,
                       const float* __restrict__ fc2w, const float* __restrict__ fc2b,
                       float* out) {
    int g = blockIdx.x;
    int j = threadIdx.x;  // 0..63
    const float* p = pooled + g * 128;
    float acc = fc1b[j];
    for (int k = 0; k < 128; ++k) acc += fmaxf(p[k], 0.f) * fc1w[k * 64 + j];
    acc = fmaxf(acc, 0.f);
    float v = acc * fc2w[j];
    for (int off = 32; off > 0; off >>= 1) v += __shfl_down(v, off, 64);
    if (j == 0) out[g] = v + fc2b[0];
}

extern "C" void kernel_launch(void* const* d_in, const int* in_sizes, int n_in,
                              void* d_out, int out_size, void* d_ws, size_t ws_size,
                              hipStream_t stream) {
    const float* x     = (const float*)d_in[0];
    const int*   ei    = (const int*)d_in[1];     // row = ei[0..E), col = ei[E..2E)
    const float* ew    = (const float*)d_in[2];
    const int*   batch = (const int*)d_in[3];
    const float* W[5], *b[5], *gm[5], *bt[5];
    for (int i = 0; i < 5; ++i) {
        W[i]  = (const float*)d_in[4 + 4 * i];
        b[i]  = (const float*)d_in[5 + 4 * i];
        gm[i] = (const float*)d_in[6 + 4 * i];
        bt[i] = (const float*)d_in[7 + 4 * i];
    }
    const float* fc1w = (const float*)d_in[24];
    const float* fc1b = (const float*)d_in[25];
    const float* fc2w = (const float*)d_in[26];
    const float* fc2b = (const float*)d_in[27];
    float* out = (float*)d_out;

    // workspace layout
    float* ws    = (float*)d_ws;
    float* dis   = ws;                       // [NN]   (deg -> dis in place)
    float* norm  = dis + NN;                 // [NE]
    float* bufA  = norm + NE;                // [NN*128] (GEMM output m)
    float* bufB  = bufA + (long)NN * 128;    // [NN*128]
    float* bufC  = bufB + (long)NN * 128;    // [NN*128]
    float* sum   = bufC + (long)NN * 128;    // [128]
    float* sumsq = sum + 128;                // [128]
    float* scale = sumsq + 128;              // [128]
    float* shift = scale + 128;              // [128]
    float* pooled = shift + 128;             // [NG*128]

    const int* row = ei;
    const int* col = ei + NE;
    const int B = 256;

    // gcn_norm
    k_init_deg<<<(NN + B - 1) / B, B, 0, stream>>>(dis, NN);
    k_deg_accum<<<(NE + B - 1) / B, B, 0, stream>>>(col, ew, dis, NE);
    k_dis<<<(NN + B - 1) / B, B, 0, stream>>>(dis, NN);
    k_norm<<<(NE + B - 1) / B, B, 0, stream>>>(row, col, ew, dis, norm, NE);

    const int din_a[5]  = {128, 16, 32, 64, 64};
    const int dout_a[5] = {16, 32, 64, 64, 128};
    const int relu_pre[5]  = {1, 1, 1, 0, 0};  // relu before BN stats (layers 1-3)
    const int relu_post[5] = {0, 0, 0, 1, 0};  // relu after BN apply (layer 4)

    const float* hin = x;
    for (int i = 0; i < 5; ++i) {
        int din = din_a[i], dout = dout_a[i];
        float* agg = (i % 2 == 0) ? bufB : bufC;
        int nd = NN * dout;
        k_gemm<<<(nd + B - 1) / B, B, 0, stream>>>(hin, W[i], bufA, NN, din, dout);
        k_selfloop<<<(nd + B - 1) / B, B, 0, stream>>>(bufA, dis, agg, NN, dout);
        long edt = (long)NE * dout;
        k_scatter<<<(int)((edt + B - 1) / B), B, 0, stream>>>(row, col, norm, bufA, agg, NE, dout);
        k_zero<<<1, 256, 0, stream>>>(sum, 256);  // zeros sum+sumsq (contiguous)
        k_bias_stats<<<1024, B, 0, stream>>>(agg, b[i], sum, sumsq, NN, dout, relu_pre[i]);
        k_bn_finalize<<<1, 128, 0, stream>>>(sum, sumsq, gm[i], bt[i], scale, shift, NN, dout);
        k_bn_apply<<<(nd + B - 1) / B, B, 0, stream>>>(agg, scale, shift, NN, dout, relu_post[i]);
        hin = agg;
    }

    // pool + head
    k_zero<<<(NG * 128 + B - 1) / B, B, 0, stream>>>(pooled, NG * 128);
    k_pool<<<(NN * 128 + B - 1) / B, B, 0, stream>>>(hin, batch, pooled, NN, 128);
    k_head<<<NG, 64, 0, stream>>>(pooled, fc1w, fc1b, fc2w, fc2b, out);
}

// Round 2
// 1070.519 us; speedup vs baseline: 1.4584x; 1.4584x over previous
//
#include <hip/hip_runtime.h>

#define NN 50000
#define NE 800000
#define NG 256

// ---------------- gcn_norm ----------------
__global__ void k_init_deg(float* deg, int n) {
    int i = blockIdx.x * blockDim.x + threadIdx.x;
    if (i < n) deg[i] = 1.0f;   // self-loop weight
}

__global__ void k_deg_accum(const int* __restrict__ col, const float* __restrict__ w,
                            float* deg, int e) {
    int i = blockIdx.x * blockDim.x + threadIdx.x;
    if (i < e) atomicAdd(&deg[col[i]], w[i]);
}

__global__ void k_dis(float* deg, int n) {
    int i = blockIdx.x * blockDim.x + threadIdx.x;
    if (i < n) {
        float d = deg[i];
        deg[i] = d > 0.f ? rsqrtf(fmaxf(d, 1e-12f)) : 0.f;  // in-place -> dis
    }
}

__global__ void k_norm(const int* __restrict__ row, const int* __restrict__ col,
                       const float* __restrict__ w, const float* __restrict__ dis,
                       float* __restrict__ norm, int e) {
    int i = blockIdx.x * blockDim.x + threadIdx.x;
    if (i < e) norm[i] = dis[row[i]] * w[i] * dis[col[i]];
}

// ---------------- CSR build (by col/target) ----------------
__global__ void k_zero_int(int* p, int n) {
    int i = blockIdx.x * blockDim.x + threadIdx.x;
    if (i < n) p[i] = 0;
}

__global__ void k_hist(const int* __restrict__ col, int* cnt, int e) {
    int i = blockIdx.x * blockDim.x + threadIdx.x;
    if (i < e) atomicAdd(&cnt[col[i]], 1);
}

// per-block exclusive scan; block totals to bsum
__global__ void k_scan1(const int* __restrict__ in, int* __restrict__ out,
                        int* __restrict__ bsum, int n) {
    __shared__ int s[256];
    int i = blockIdx.x * 256 + threadIdx.x;
    int v = (i < n) ? in[i] : 0;
    s[threadIdx.x] = v;
    __syncthreads();
    for (int off = 1; off < 256; off <<= 1) {
        int t = (threadIdx.x >= off) ? s[threadIdx.x - off] : 0;
        __syncthreads();
        s[threadIdx.x] += t;
        __syncthreads();
    }
    if (i < n) out[i] = s[threadIdx.x] - v;  // exclusive
    if (threadIdx.x == 255) bsum[blockIdx.x] = s[255];
}

// single block: exclusive scan of bsum (nb <= 256)
__global__ void k_scan2(int* bsum, int nb) {
    __shared__ int s[256];
    int v = (threadIdx.x < nb) ? bsum[threadIdx.x] : 0;
    s[threadIdx.x] = v;
    __syncthreads();
    for (int off = 1; off < 256; off <<= 1) {
        int t = (threadIdx.x >= off) ? s[threadIdx.x - off] : 0;
        __syncthreads();
        s[threadIdx.x] += t;
        __syncthreads();
    }
    if (threadIdx.x < nb) bsum[threadIdx.x] = s[threadIdx.x] - v;
}

__global__ void k_scan3(int* __restrict__ ptr, const int* __restrict__ bsum, int n, int total) {
    int i = blockIdx.x * 256 + threadIdx.x;
    if (i < n) ptr[i] += bsum[blockIdx.x];
    if (i == 0) ptr[n] = total;
}

__global__ void k_copy_int(const int* __restrict__ a, int* __restrict__ b, int n) {
    int i = blockIdx.x * blockDim.x + threadIdx.x;
    if (i < n) b[i] = a[i];
}

__global__ void k_fill(const int* __restrict__ row, const int* __restrict__ col,
                       const float* __restrict__ norm, int* cursor,
                       int* __restrict__ csr_src, float* __restrict__ csr_w, int e) {
    int i = blockIdx.x * blockDim.x + threadIdx.x;
    if (i < e) {
        int c = col[i];
        int p = atomicAdd(&cursor[c], 1);
        csr_src[p] = row[i];
        csr_w[p] = norm[i];
    }
}

// ---------------- aggregation: gather form, self-loop fused ----------------
// out[c,j] = dis[c]^2 * src[c,j] + sum_{p in [ptr[c],ptr[c+1])} csr_w[p]*src[csr_src[p],j]
template <int D>
__global__ void k_gather(const float* __restrict__ src, const int* __restrict__ ptr,
                         const int* __restrict__ csr_src, const float* __restrict__ csr_w,
                         const float* __restrict__ dis, float* __restrict__ out, int n) {
    int t = blockIdx.x * blockDim.x + threadIdx.x;
    int node = t / D;
    int j = t - node * D;
    if (node >= n) return;
    float d = dis[node];
    float acc = src[(long)node * D + j] * d * d;
    int p0 = ptr[node], p1 = ptr[node + 1];
    for (int p = p0; p < p1; ++p) {
        int s = csr_src[p];
        float w = csr_w[p];
        acc += w * src[(long)s * D + j];
    }
    out[(long)node * D + j] = acc;
}

// ---------------- dense transform, W staged in LDS ----------------
template <int DIN, int DOUT>
__global__ void k_gemm2(const float* __restrict__ h, const float* __restrict__ W,
                        float* __restrict__ m, int n) {
    __shared__ float Wl[DIN * DOUT];
    for (int i = threadIdx.x; i < DIN * DOUT; i += blockDim.x) Wl[i] = W[i];
    __syncthreads();
    int t = blockIdx.x * blockDim.x + threadIdx.x;
    int node = t / DOUT;
    int j = t - node * DOUT;
    if (node >= n) return;
    const float* hr = h + (long)node * DIN;
    float acc = 0.f;
#pragma unroll 4
    for (int k = 0; k < DIN; ++k) acc += hr[k] * Wl[k * DOUT + j];
    m[t] = acc;
}

// ---------------- BN pieces ----------------
__global__ void k_zero(float* p, int n) {
    int i = blockIdx.x * blockDim.x + threadIdx.x;
    if (i < n) p[i] = 0.f;
}

__global__ void k_bias_stats(float* h, const float* __restrict__ b,
                             float* sum, float* sumsq, int n, int dout, int relu) {
    __shared__ float ls[128], lq[128];
    int tid = threadIdx.x;
    if (tid < dout) { ls[tid] = 0.f; lq[tid] = 0.f; }
    __syncthreads();
    int total = n * dout;
    int stride = gridDim.x * blockDim.x;   // multiple of dout
    float s = 0.f, q = 0.f;
    int j = -1;
    for (int t = blockIdx.x * blockDim.x + tid; t < total; t += stride) {
        int jj = t % dout;
        j = jj;
        float v = h[t] + b[jj];
        if (relu) v = fmaxf(v, 0.f);
        h[t] = v;
        s += v;
        q += v * v;
    }
    if (j >= 0) { atomicAdd(&ls[j], s); atomicAdd(&lq[j], q); }
    __syncthreads();
    if (tid < dout) {
        atomicAdd(&sum[tid], ls[tid]);
        atomicAdd(&sumsq[tid], lq[tid]);
    }
}

__global__ void k_bn_finalize(const float* sum, const float* sumsq,
                              const float* __restrict__ g, const float* __restrict__ bt,
                              float* scale, float* shift, int n, int dout) {
    int j = threadIdx.x;
    if (j >= dout) return;
    float mu = sum[j] / n;
    float var = sumsq[j] / n - mu * mu;
    float a = g[j] * rsqrtf(var + 1e-5f);
    scale[j] = a;
    shift[j] = bt[j] - mu * a;
}

__global__ void k_bn_apply(float* h, const float* __restrict__ scale,
                           const float* __restrict__ shift, int n, int dout, int relu) {
    int t = blockIdx.x * blockDim.x + threadIdx.x;
    if (t >= n * dout) return;
    int j = t % dout;
    float v = scale[j] * h[t] + shift[j];
    if (relu) v = fmaxf(v, 0.f);
    h[t] = v;
}

// ---------------- pool + head ----------------
__global__ void k_pool(const float* __restrict__ h, const int* __restrict__ batch,
                       float* pooled, int n, int dout) {
    int t = blockIdx.x * blockDim.x + threadIdx.x;
    if (t >= n * dout) return;
    int node = t / dout;
    int j = t - node * dout;
    atomicAdd(&pooled[batch[node] * dout + j], h[t]);
}

__global__ void k_head(const float* __restrict__ pooled,
                       const float* __restrict__ fc1w, const float* __restrict__ fc1b,
                       const float* __restrict__ fc2w, const float* __restrict__ fc2b,
                       float* out) {
    int g = blockIdx.x;
    int j = threadIdx.x;  // 0..63
    const float* p = pooled + g * 128;
    float acc = fc1b[j];
    for (int k = 0; k < 128; ++k) acc += fmaxf(p[k], 0.f) * fc1w[k * 64 + j];
    acc = fmaxf(acc, 0.f);
    float v = acc * fc2w[j];
    for (int off = 32; off > 0; off >>= 1) v += __shfl_down(v, off, 64);
    if (j == 0) out[g] = v + fc2b[0];
}

// ---------------- driver ----------------
extern "C" void kernel_launch(void* const* d_in, const int* in_sizes, int n_in,
                              void* d_out, int out_size, void* d_ws, size_t ws_size,
                              hipStream_t stream) {
    const float* x     = (const float*)d_in[0];
    const int*   ei    = (const int*)d_in[1];
    const float* ew    = (const float*)d_in[2];
    const int*   batch = (const int*)d_in[3];
    const float *W[5], *b[5], *gm[5], *bt[5];
    for (int i = 0; i < 5; ++i) {
        W[i]  = (const float*)d_in[4 + 4 * i];
        b[i]  = (const float*)d_in[5 + 4 * i];
        gm[i] = (const float*)d_in[6 + 4 * i];
        bt[i] = (const float*)d_in[7 + 4 * i];
    }
    const float* fc1w = (const float*)d_in[24];
    const float* fc1b = (const float*)d_in[25];
    const float* fc2w = (const float*)d_in[26];
    const float* fc2b = (const float*)d_in[27];
    float* out = (float*)d_out;

    // workspace layout
    char* wsb = (char*)d_ws;
    float* dis    = (float*)wsb;                 wsb += sizeof(float) * NN;
    float* norm   = (float*)wsb;                 wsb += sizeof(float) * NE;
    int*   ptr    = (int*)wsb;                   wsb += sizeof(int) * (NN + 1);
    int*   cursor = (int*)wsb;                   wsb += sizeof(int) * NN;
    int*   bsum   = (int*)wsb;                   wsb += sizeof(int) * 256;
    int*   csr_src= (int*)wsb;                   wsb += sizeof(int) * NE;
    float* csr_w  = (float*)wsb;                 wsb += sizeof(float) * NE;
    float* buf1   = (float*)wsb;                 wsb += sizeof(float) * (long)NN * 128;
    float* buf2   = (float*)wsb;                 wsb += sizeof(float) * (long)NN * 128;
    float* sum    = (float*)wsb;                 wsb += sizeof(float) * 128;
    float* sumsq  = (float*)wsb;                 wsb += sizeof(float) * 128;
    float* scale  = (float*)wsb;                 wsb += sizeof(float) * 128;
    float* shift  = (float*)wsb;                 wsb += sizeof(float) * 128;
    float* pooled = (float*)wsb;                 wsb += sizeof(float) * NG * 128;

    const int* row = ei;
    const int* col = ei + NE;
    const int B = 256;
    const int NB_N = (NN + B - 1) / B;       // 196
    const int NB_E = (NE + B - 1) / B;

    // gcn_norm
    k_init_deg<<<NB_N, B, 0, stream>>>(dis, NN);
    k_deg_accum<<<NB_E, B, 0, stream>>>(col, ew, dis, NE);
    k_dis<<<NB_N, B, 0, stream>>>(dis, NN);
    k_norm<<<NB_E, B, 0, stream>>>(row, col, ew, dis, norm, NE);

    // CSR build (target-sorted)
    k_zero_int<<<NB_N, B, 0, stream>>>(cursor, NN);
    k_hist<<<NB_E, B, 0, stream>>>(col, cursor, NE);
    k_scan1<<<NB_N, B, 0, stream>>>(cursor, ptr, bsum, NN);
    k_scan2<<<1, 256, 0, stream>>>(bsum, NB_N);
    k_scan3<<<NB_N, B, 0, stream>>>(ptr, bsum, NN, NE);
    k_copy_int<<<NB_N, B, 0, stream>>>(ptr, cursor, NN);
    k_fill<<<NB_E, B, 0, stream>>>(row, col, norm, cursor, csr_src, csr_w, NE);

    auto postproc = [&](float* buf, int dout, int i, int relu_pre, int relu_post) {
        int nd = NN * dout;
        k_zero<<<1, 256, 0, stream>>>(sum, 256);  // sum+sumsq contiguous
        k_bias_stats<<<1024, B, 0, stream>>>(buf, b[i], sum, sumsq, NN, dout, relu_pre);
        k_bn_finalize<<<1, 128, 0, stream>>>(sum, sumsq, gm[i], bt[i], scale, shift, NN, dout);
        k_bn_apply<<<(nd + B - 1) / B, B, 0, stream>>>(buf, scale, shift, NN, dout, relu_post);
    };

    // L1: transform (128->16) then aggregate in 16 dims
    k_gemm2<128, 16><<<(NN * 16 + B - 1) / B, B, 0, stream>>>(x, W[0], buf1, NN);
    k_gather<16><<<(NN * 16 + B - 1) / B, B, 0, stream>>>(buf1, ptr, csr_src, csr_w, dis, buf2, NN);
    postproc(buf2, 16, 0, 1, 0);

    // L2: aggregate in 16, transform 16->32
    k_gather<16><<<(NN * 16 + B - 1) / B, B, 0, stream>>>(buf2, ptr, csr_src, csr_w, dis, buf1, NN);
    k_gemm2<16, 32><<<(NN * 32 + B - 1) / B, B, 0, stream>>>(buf1, W[1], buf2, NN);
    postproc(buf2, 32, 1, 1, 0);

    // L3: aggregate in 32, transform 32->64
    k_gather<32><<<(NN * 32 + B - 1) / B, B, 0, stream>>>(buf2, ptr, csr_src, csr_w, dis, buf1, NN);
    k_gemm2<32, 64><<<(NN * 64 + B - 1) / B, B, 0, stream>>>(buf1, W[2], buf2, NN);
    postproc(buf2, 64, 2, 1, 0);

    // L4: aggregate in 64, transform 64->64, conv->bn->relu
    k_gather<64><<<(NN * 64 + B - 1) / B, B, 0, stream>>>(buf2, ptr, csr_src, csr_w, dis, buf1, NN);
    k_gemm2<64, 64><<<(NN * 64 + B - 1) / B, B, 0, stream>>>(buf1, W[3], buf2, NN);
    postproc(buf2, 64, 3, 0, 1);

    // L5: aggregate in 64, transform 64->128, conv->bn
    k_gather<64><<<(NN * 64 + B - 1) / B, B, 0, stream>>>(buf2, ptr, csr_src, csr_w, dis, buf1, NN);
    k_gemm2<64, 128><<<(NN * 128 + B - 1) / B, B, 0, stream>>>(buf1, W[4], buf2, NN);
    postproc(buf2, 128, 4, 0, 0);

    // pool + head
    k_zero<<<(NG * 128 + B - 1) / B, B, 0, stream>>>(pooled, NG * 128);
    k_pool<<<(NN * 128 + B - 1) / B, B, 0, stream>>>(buf2, batch, pooled, NN, 128);
    k_head<<<NG, 64, 0, stream>>>(pooled, fc1w, fc1b, fc2w, fc2b, out);
}

// Round 3
// 615.688 us; speedup vs baseline: 2.5358x; 1.7387x over previous
//
#include <hip/hip_runtime.h>

#define NN 50000
#define NE 800000
#define NG 256
#define NBUCKET 64

// ---------------- gcn_norm ----------------
__global__ void k_init_deg(float* deg, int n) {
    int i = blockIdx.x * blockDim.x + threadIdx.x;
    if (i < n) deg[i] = 1.0f;   // self-loop weight
}

__global__ void k_deg_accum(const int* __restrict__ col, const float* __restrict__ w,
                            float* deg, int e) {
    int i = blockIdx.x * blockDim.x + threadIdx.x;
    if (i < e) atomicAdd(&deg[col[i]], w[i]);
}

__global__ void k_dis(float* deg, int n) {
    int i = blockIdx.x * blockDim.x + threadIdx.x;
    if (i < n) {
        float d = deg[i];
        deg[i] = d > 0.f ? rsqrtf(fmaxf(d, 1e-12f)) : 0.f;  // in-place -> dis
    }
}

// ---------------- CSR build (by col/target) ----------------
__global__ void k_zero_int(int* p, int n) {
    int i = blockIdx.x * blockDim.x + threadIdx.x;
    if (i < n) p[i] = 0;
}

__global__ void k_zero_f(float* p, int n) {
    int i = blockIdx.x * blockDim.x + threadIdx.x;
    if (i < n) p[i] = 0.f;
}

__global__ void k_hist(const int* __restrict__ col, int* cnt, int e) {
    int i = blockIdx.x * blockDim.x + threadIdx.x;
    if (i < e) atomicAdd(&cnt[col[i]], 1);
}

__global__ void k_scan1(const int* __restrict__ in, int* __restrict__ out,
                        int* __restrict__ bsum, int n) {
    __shared__ int s[256];
    int i = blockIdx.x * 256 + threadIdx.x;
    int v = (i < n) ? in[i] : 0;
    s[threadIdx.x] = v;
    __syncthreads();
    for (int off = 1; off < 256; off <<= 1) {
        int t = (threadIdx.x >= off) ? s[threadIdx.x - off] : 0;
        __syncthreads();
        s[threadIdx.x] += t;
        __syncthreads();
    }
    if (i < n) out[i] = s[threadIdx.x] - v;  // exclusive
    if (threadIdx.x == 255) bsum[blockIdx.x] = s[255];
}

__global__ void k_scan2(int* bsum, int nb) {
    __shared__ int s[256];
    int v = (threadIdx.x < nb) ? bsum[threadIdx.x] : 0;
    s[threadIdx.x] = v;
    __syncthreads();
    for (int off = 1; off < 256; off <<= 1) {
        int t = (threadIdx.x >= off) ? s[threadIdx.x - off] : 0;
        __syncthreads();
        s[threadIdx.x] += t;
        __syncthreads();
    }
    if (threadIdx.x < nb) bsum[threadIdx.x] = s[threadIdx.x] - v;
}

__global__ void k_scan3(int* __restrict__ ptr, const int* __restrict__ bsum, int n, int total) {
    int i = blockIdx.x * 256 + threadIdx.x;
    if (i < n) ptr[i] += bsum[blockIdx.x];
    if (i == 0) ptr[n] = total;
}

__global__ void k_copy_int(const int* __restrict__ a, int* __restrict__ b, int n) {
    int i = blockIdx.x * blockDim.x + threadIdx.x;
    if (i < n) b[i] = a[i];
}

// fill CSR; compute edge norm inline: dis[row]*w*dis[col]
__global__ void k_fill(const int* __restrict__ row, const int* __restrict__ col,
                       const float* __restrict__ ew, const float* __restrict__ dis,
                       int* cursor, int* __restrict__ csr_src, float* __restrict__ csr_w, int e) {
    int i = blockIdx.x * blockDim.x + threadIdx.x;
    if (i < e) {
        int r = row[i], c = col[i];
        int p = atomicAdd(&cursor[c], 1);
        csr_src[p] = r;
        csr_w[p] = dis[r] * ew[i] * dis[c];
    }
}

// ---------------- gather (float4/thread), optional input affine(+relu), optional L1 epilogue ----
// EPI path (L1 only): out = relu(agg + bias), accumulate channel stats into buckets.
template <int D, int AFFINE, int RELUPOST, int EPI>
__global__ void k_gather(const float* __restrict__ src, const int* __restrict__ ptr,
                         const int* __restrict__ csr_src, const float* __restrict__ csr_w,
                         const float* __restrict__ dis,
                         const float* __restrict__ scale, const float* __restrict__ shift,
                         const float* __restrict__ bias, float* __restrict__ part,
                         float* __restrict__ out, int n) {
    const int TPN = D / 4;
    __shared__ float ls[EPI ? D : 1], lq[EPI ? D : 1];
    int tid = threadIdx.x;
    if (EPI) {
        if (tid < D) { ls[tid] = 0.f; lq[tid] = 0.f; }
        __syncthreads();
    }
    int t = blockIdx.x * blockDim.x + tid;
    int node = t / TPN;
    int l4 = t - node * TPN;           // float4 index within row (== tid % TPN)
    bool valid = node < n;
    int nc = valid ? node : n - 1;

    float4 sc = {0,0,0,0}, sh = {0,0,0,0};
    if (AFFINE) {
        sc = ((const float4*)scale)[l4];
        sh = ((const float4*)shift)[l4];
    }
    const float4* s4 = (const float4*)src;
    float d = dis[nc];
    float4 v = s4[(long)nc * TPN + l4];
    if (AFFINE) {
        v.x = sc.x * v.x + sh.x; v.y = sc.y * v.y + sh.y;
        v.z = sc.z * v.z + sh.z; v.w = sc.w * v.w + sh.w;
        if (RELUPOST) {
            v.x = fmaxf(v.x, 0.f); v.y = fmaxf(v.y, 0.f);
            v.z = fmaxf(v.z, 0.f); v.w = fmaxf(v.w, 0.f);
        }
    }
    float w0 = d * d;
    float4 acc = { w0 * v.x, w0 * v.y, w0 * v.z, w0 * v.w };
    int p0 = ptr[nc], p1 = ptr[nc + 1];
    for (int p = p0; p < p1; ++p) {
        int s = csr_src[p];
        float w = csr_w[p];
        float4 u = s4[(long)s * TPN + l4];
        if (AFFINE) {
            u.x = sc.x * u.x + sh.x; u.y = sc.y * u.y + sh.y;
            u.z = sc.z * u.z + sh.z; u.w = sc.w * u.w + sh.w;
            if (RELUPOST) {
                u.x = fmaxf(u.x, 0.f); u.y = fmaxf(u.y, 0.f);
                u.z = fmaxf(u.z, 0.f); u.w = fmaxf(u.w, 0.f);
            }
        }
        acc.x += w * u.x; acc.y += w * u.y; acc.z += w * u.z; acc.w += w * u.w;
    }
    if (EPI) {
        float4 b = ((const float4*)bias)[l4];
        acc.x = fmaxf(acc.x + b.x, 0.f);
        acc.y = fmaxf(acc.y + b.y, 0.f);
        acc.z = fmaxf(acc.z + b.z, 0.f);
        acc.w = fmaxf(acc.w + b.w, 0.f);
        if (valid) ((float4*)out)[(long)nc * TPN + l4] = acc;
        float s0 = valid ? acc.x : 0.f, s1 = valid ? acc.y : 0.f;
        float s2 = valid ? acc.z : 0.f, s3 = valid ? acc.w : 0.f;
        float q0 = s0*s0, q1 = s1*s1, q2 = s2*s2, q3 = s3*s3;
        for (int off = TPN; off < 64; off <<= 1) {
            s0 += __shfl_down(s0, off, 64); s1 += __shfl_down(s1, off, 64);
            s2 += __shfl_down(s2, off, 64); s3 += __shfl_down(s3, off, 64);
            q0 += __shfl_down(q0, off, 64); q1 += __shfl_down(q1, off, 64);
            q2 += __shfl_down(q2, off, 64); q3 += __shfl_down(q3, off, 64);
        }
        int lane = tid & 63;
        if (lane < TPN) {
            atomicAdd(&ls[4*lane+0], s0); atomicAdd(&ls[4*lane+1], s1);
            atomicAdd(&ls[4*lane+2], s2); atomicAdd(&ls[4*lane+3], s3);
            atomicAdd(&lq[4*lane+0], q0); atomicAdd(&lq[4*lane+1], q1);
            atomicAdd(&lq[4*lane+2], q2); atomicAdd(&lq[4*lane+3], q3);
        }
        __syncthreads();
        int bkt = (blockIdx.x & (NBUCKET - 1)) * 256;
        if (tid < D) {
            atomicAdd(&part[bkt + tid], ls[tid]);
            atomicAdd(&part[bkt + 128 + tid], lq[tid]);
        }
    } else {
        if (valid) ((float4*)out)[(long)nc * TPN + l4] = acc;
    }
}

// ---------------- register-tiled GEMM: 4 outputs/thread, W in LDS ----------------
// EPI: v = acc + bias, optional relu, store, accumulate channel stats (bucketed).
template <int DIN, int DOUT, int RELU, int EPI>
__global__ void k_gemm(const float* __restrict__ h, const float* __restrict__ W,
                       const float* __restrict__ bias, float* __restrict__ part,
                       float* __restrict__ m, int n) {
    const int TPN = DOUT / 4;
    __shared__ float Wl[DIN * DOUT];
    __shared__ float ls[EPI ? DOUT : 1], lq[EPI ? DOUT : 1];
    int tid = threadIdx.x;
    for (int i = tid; i < DIN * DOUT / 4; i += blockDim.x)
        ((float4*)Wl)[i] = ((const float4*)W)[i];
    if (EPI && tid < DOUT) { ls[tid] = 0.f; lq[tid] = 0.f; }
    __syncthreads();

    int t = blockIdx.x * blockDim.x + tid;
    int node = t / TPN;
    int jq = t - node * TPN;     // float4 index within output row
    bool valid = node < n;
    int nc = valid ? node : n - 1;
    const float4* h4 = (const float4*)(h + (long)nc * DIN);
    float4 acc = {0,0,0,0};
#pragma unroll
    for (int k4 = 0; k4 < DIN / 4; ++k4) {
        float4 hv = h4[k4];
        const float* wb = &Wl[(k4 * 4) * DOUT + jq * 4];
        float4 w0 = *(const float4*)(wb);
        float4 w1 = *(const float4*)(wb + DOUT);
        float4 w2 = *(const float4*)(wb + 2 * DOUT);
        float4 w3 = *(const float4*)(wb + 3 * DOUT);
        acc.x += hv.x*w0.x + hv.y*w1.x + hv.z*w2.x + hv.w*w3.x;
        acc.y += hv.x*w0.y + hv.y*w1.y + hv.z*w2.y + hv.w*w3.y;
        acc.z += hv.x*w0.z + hv.y*w1.z + hv.z*w2.z + hv.w*w3.z;
        acc.w += hv.x*w0.w + hv.y*w1.w + hv.z*w2.w + hv.w*w3.w;
    }
    if (EPI) {
        float4 b = ((const float4*)bias)[jq];
        acc.x += b.x; acc.y += b.y; acc.z += b.z; acc.w += b.w;
        if (RELU) {
            acc.x = fmaxf(acc.x, 0.f); acc.y = fmaxf(acc.y, 0.f);
            acc.z = fmaxf(acc.z, 0.f); acc.w = fmaxf(acc.w, 0.f);
        }
    }
    if (valid) ((float4*)m)[(long)nc * TPN + jq] = acc;
    if (EPI) {
        float s0 = valid ? acc.x : 0.f, s1 = valid ? acc.y : 0.f;
        float s2 = valid ? acc.z : 0.f, s3 = valid ? acc.w : 0.f;
        float q0 = s0*s0, q1 = s1*s1, q2 = s2*s2, q3 = s3*s3;
        for (int off = TPN; off < 64; off <<= 1) {
            s0 += __shfl_down(s0, off, 64); s1 += __shfl_down(s1, off, 64);
            s2 += __shfl_down(s2, off, 64); s3 += __shfl_down(s3, off, 64);
            q0 += __shfl_down(q0, off, 64); q1 += __shfl_down(q1, off, 64);
            q2 += __shfl_down(q2, off, 64); q3 += __shfl_down(q3, off, 64);
        }
        int lane = tid & 63;
        if (lane < TPN) {
            atomicAdd(&ls[4*lane+0], s0); atomicAdd(&ls[4*lane+1], s1);
            atomicAdd(&ls[4*lane+2], s2); atomicAdd(&ls[4*lane+3], s3);
            atomicAdd(&lq[4*lane+0], q0); atomicAdd(&lq[4*lane+1], q1);
            atomicAdd(&lq[4*lane+2], q2); atomicAdd(&lq[4*lane+3], q3);
        }
        __syncthreads();
        int bkt = (blockIdx.x & (NBUCKET - 1)) * 256;
        if (tid < DOUT) {
            atomicAdd(&part[bkt + tid], ls[tid]);
            atomicAdd(&part[bkt + 128 + tid], lq[tid]);
        }
    }
}

// ---------------- BN finalize: reduce buckets -> scale/shift, self-zero buckets ----
__global__ void k_finalize(float* part, const float* __restrict__ g, const float* __restrict__ bt,
                           float* scale, float* shift, int dout, int n) {
    int j = threadIdx.x;
    if (j >= dout) return;
    float s = 0.f, q = 0.f;
    for (int b = 0; b < NBUCKET; ++b) {
        s += part[b * 256 + j];       part[b * 256 + j] = 0.f;
        q += part[b * 256 + 128 + j]; part[b * 256 + 128 + j] = 0.f;
    }
    float mu = s / n;
    float var = q / n - mu * mu;
    float a = g[j] * rsqrtf(var + 1e-5f);
    scale[j] = a;
    shift[j] = bt[j] - mu * a;
}

// ---------------- pool with L5 BN applied on the fly ----------------
__global__ void k_pool(const float* __restrict__ h, const int* __restrict__ batch,
                       const float* __restrict__ scale, const float* __restrict__ shift,
                       float* pooled, int n) {
    int t = blockIdx.x * blockDim.x + threadIdx.x;
    if (t >= n * 128) return;
    int node = t >> 7;
    int j = t & 127;
    float v = scale[j] * h[t] + shift[j];
    atomicAdd(&pooled[(batch[node] << 7) + j], v);
}

__global__ void k_head(const float* __restrict__ pooled,
                       const float* __restrict__ fc1w, const float* __restrict__ fc1b,
                       const float* __restrict__ fc2w, const float* __restrict__ fc2b,
                       float* out) {
    int g = blockIdx.x;
    int j = threadIdx.x;  // 0..63
    const float* p = pooled + g * 128;
    float acc = fc1b[j];
    for (int k = 0; k < 128; ++k) acc += fmaxf(p[k], 0.f) * fc1w[k * 64 + j];
    acc = fmaxf(acc, 0.f);
    float v = acc * fc2w[j];
    for (int off = 32; off > 0; off >>= 1) v += __shfl_down(v, off, 64);
    if (j == 0) out[g] = v + fc2b[0];
}

// ---------------- driver ----------------
extern "C" void kernel_launch(void* const* d_in, const int* in_sizes, int n_in,
                              void* d_out, int out_size, void* d_ws, size_t ws_size,
                              hipStream_t stream) {
    const float* x     = (const float*)d_in[0];
    const int*   ei    = (const int*)d_in[1];
    const float* ew    = (const float*)d_in[2];
    const int*   batch = (const int*)d_in[3];
    const float *W[5], *b[5], *gm[5], *bt[5];
    for (int i = 0; i < 5; ++i) {
        W[i]  = (const float*)d_in[4 + 4 * i];
        b[i]  = (const float*)d_in[5 + 4 * i];
        gm[i] = (const float*)d_in[6 + 4 * i];
        bt[i] = (const float*)d_in[7 + 4 * i];
    }
    const float* fc1w = (const float*)d_in[24];
    const float* fc1b = (const float*)d_in[25];
    const float* fc2w = (const float*)d_in[26];
    const float* fc2b = (const float*)d_in[27];
    float* out = (float*)d_out;

    // workspace layout
    char* wsb = (char*)d_ws;
    float* dis    = (float*)wsb;  wsb += sizeof(float) * NN;
    int*   ptr    = (int*)wsb;    wsb += sizeof(int) * (NN + 1);
    int*   cursor = (int*)wsb;    wsb += sizeof(int) * NN;
    int*   bsum   = (int*)wsb;    wsb += sizeof(int) * 256;
    int*   csr_src= (int*)wsb;    wsb += sizeof(int) * NE;
    float* csr_w  = (float*)wsb;  wsb += sizeof(float) * NE;
    float* part   = (float*)wsb;  wsb += sizeof(float) * NBUCKET * 256;   // [64][2][128]
    float* pooled = (float*)wsb;  wsb += sizeof(float) * NG * 128;        // adjacent to part for one zero-kernel
    float* scl    = (float*)wsb;  wsb += sizeof(float) * 5 * 128;
    float* shf    = (float*)wsb;  wsb += sizeof(float) * 5 * 128;
    float* buf1   = (float*)wsb;  wsb += sizeof(float) * (long)NN * 128;
    float* buf2   = (float*)wsb;  wsb += sizeof(float) * (long)NN * 128;

    const int* row = ei;
    const int* col = ei + NE;
    const int B = 256;
    const int NB_N = (NN + B - 1) / B;   // 196
    const int NB_E = (NE + B - 1) / B;

    // gcn_norm + CSR build
    k_init_deg<<<NB_N, B, 0, stream>>>(dis, NN);
    k_deg_accum<<<NB_E, B, 0, stream>>>(col, ew, dis, NE);
    k_dis<<<NB_N, B, 0, stream>>>(dis, NN);
    k_zero_int<<<NB_N, B, 0, stream>>>(cursor, NN);
    k_hist<<<NB_E, B, 0, stream>>>(col, cursor, NE);
    k_scan1<<<NB_N, B, 0, stream>>>(cursor, ptr, bsum, NN);
    k_scan2<<<1, 256, 0, stream>>>(bsum, NB_N);
    k_scan3<<<NB_N, B, 0, stream>>>(ptr, bsum, NN, NE);
    k_copy_int<<<NB_N, B, 0, stream>>>(ptr, cursor, NN);
    k_fill<<<NB_E, B, 0, stream>>>(row, col, ew, dis, cursor, csr_src, csr_w, NE);

    // zero stats buckets + pooled (contiguous): 64*256 + 256*128 floats
    k_zero_f<<<(NBUCKET * 256 + NG * 128 + B - 1) / B, B, 0, stream>>>(part, NBUCKET * 256 + NG * 128);

    auto grid4 = [](long threads) { return (int)((threads + 255) / 256); };

    // L1: gemm 128->16 (raw), gather16 + bias+relu+stats
    k_gemm<128, 16, 0, 0><<<grid4((long)NN * 4), B, 0, stream>>>(x, W[0], b[0], part, buf1, NN);
    k_gather<16, 0, 0, 1><<<grid4((long)NN * 4), B, 0, stream>>>(buf1, ptr, csr_src, csr_w, dis,
                                                                 nullptr, nullptr, b[0], part, buf2, NN);
    k_finalize<<<1, 128, 0, stream>>>(part, gm[0], bt[0], scl + 0, shf + 0, 16, NN);

    // L2: gather16 (BN1 on the fly), gemm 16->32 + bias+relu+stats
    k_gather<16, 1, 0, 0><<<grid4((long)NN * 4), B, 0, stream>>>(buf2, ptr, csr_src, csr_w, dis,
                                                                 scl + 0, shf + 0, nullptr, nullptr, buf1, NN);
    k_gemm<16, 32, 1, 1><<<grid4((long)NN * 8), B, 0, stream>>>(buf1, W[1], b[1], part, buf2, NN);
    k_finalize<<<1, 128, 0, stream>>>(part, gm[1], bt[1], scl + 128, shf + 128, 32, NN);

    // L3: gather32 (BN2), gemm 32->64 + bias+relu+stats
    k_gather<32, 1, 0, 0><<<grid4((long)NN * 8), B, 0, stream>>>(buf2, ptr, csr_src, csr_w, dis,
                                                                 scl + 128, shf + 128, nullptr, nullptr, buf1, NN);
    k_gemm<32, 64, 1, 1><<<grid4((long)NN * 16), B, 0, stream>>>(buf1, W[2], b[2], part, buf2, NN);
    k_finalize<<<1, 128, 0, stream>>>(part, gm[2], bt[2], scl + 256, shf + 256, 64, NN);

    // L4: gather64 (BN3), gemm 64->64 + bias+stats (relu is post-BN)
    k_gather<64, 1, 0, 0><<<grid4((long)NN * 16), B, 0, stream>>>(buf2, ptr, csr_src, csr_w, dis,
                                                                  scl + 256, shf + 256, nullptr, nullptr, buf1, NN);
    k_gemm<64, 64, 0, 1><<<grid4((long)NN * 16), B, 0, stream>>>(buf1, W[3], b[3], part, buf2, NN);
    k_finalize<<<1, 128, 0, stream>>>(part, gm[3], bt[3], scl + 384, shf + 384, 64, NN);

    // L5: gather64 (BN4 + post-relu), gemm 64->128 + bias+stats
    k_gather<64, 1, 1, 0><<<grid4((long)NN * 16), B, 0, stream>>>(buf2, ptr, csr_src, csr_w, dis,
                                                                  scl + 384, shf + 384, nullptr, nullptr, buf1, NN);
    k_gemm<64, 128, 0, 1><<<grid4((long)NN * 32), B, 0, stream>>>(buf1, W[4], b[4], part, buf2, NN);
    k_finalize<<<1, 128, 0, stream>>>(part, gm[4], bt[4], scl + 512, shf + 512, 128, NN);

    // pool (BN5 on the fly) + head
    k_pool<<<grid4((long)NN * 128), B, 0, stream>>>(buf2, batch, scl + 512, shf + 512, pooled, NN);
    k_head<<<NG, 64, 0, stream>>>(pooled, fc1w, fc1b, fc2w, fc2b, out);
}

// Round 4
// 543.812 us; speedup vs baseline: 2.8710x; 1.1322x over previous
//
#include <hip/hip_runtime.h>

#define NN 50000
#define NE 800000
#define NG 256
#define NBUCKET 64

// ---------------- prologue ----------------
// deg=1 (self loop), cursor=0, part buckets = 0
__global__ void k_init(float* deg, int* cursor, float* part, int n) {
    int i = blockIdx.x * blockDim.x + threadIdx.x;
    if (i < n) { deg[i] = 1.0f; cursor[i] = 0; }
    if (i < NBUCKET * 256) part[i] = 0.f;
}

// weighted degree + edge count histogram in one pass
__global__ void k_edge(const int* __restrict__ col, const float* __restrict__ ew,
                       float* deg, int* cnt, int e) {
    int i = blockIdx.x * blockDim.x + threadIdx.x;
    if (i < e) {
        int c = col[i];
        atomicAdd(&deg[c], ew[i]);
        atomicAdd(&cnt[c], 1);
    }
}

__global__ void k_dis(float* deg, int n) {
    int i = blockIdx.x * blockDim.x + threadIdx.x;
    if (i < n) {
        float d = deg[i];
        deg[i] = d > 0.f ? rsqrtf(fmaxf(d, 1e-12f)) : 0.f;  // in-place -> dis
    }
}

__global__ void k_scan1(const int* __restrict__ in, int* __restrict__ out,
                        int* __restrict__ bsum, int n) {
    __shared__ int s[256];
    int i = blockIdx.x * 256 + threadIdx.x;
    int v = (i < n) ? in[i] : 0;
    s[threadIdx.x] = v;
    __syncthreads();
    for (int off = 1; off < 256; off <<= 1) {
        int t = (threadIdx.x >= off) ? s[threadIdx.x - off] : 0;
        __syncthreads();
        s[threadIdx.x] += t;
        __syncthreads();
    }
    if (i < n) out[i] = s[threadIdx.x] - v;  // exclusive
    if (threadIdx.x == 255) bsum[blockIdx.x] = s[255];
}

__global__ void k_scan2(int* bsum, int nb) {
    __shared__ int s[256];
    int v = (threadIdx.x < nb) ? bsum[threadIdx.x] : 0;
    s[threadIdx.x] = v;
    __syncthreads();
    for (int off = 1; off < 256; off <<= 1) {
        int t = (threadIdx.x >= off) ? s[threadIdx.x - off] : 0;
        __syncthreads();
        s[threadIdx.x] += t;
        __syncthreads();
    }
    if (threadIdx.x < nb) bsum[threadIdx.x] = s[threadIdx.x] - v;
}

__global__ void k_scan3(int* __restrict__ ptr, const int* __restrict__ bsum, int n, int total) {
    int i = blockIdx.x * 256 + threadIdx.x;
    if (i < n) ptr[i] += bsum[blockIdx.x];
    if (i == 0) ptr[n] = total;
}

__global__ void k_copy_int(const int* __restrict__ a, int* __restrict__ b, int n) {
    int i = blockIdx.x * blockDim.x + threadIdx.x;
    if (i < n) b[i] = a[i];
}

__global__ void k_fill(const int* __restrict__ row, const int* __restrict__ col,
                       const float* __restrict__ ew, const float* __restrict__ dis,
                       int* cursor, int* __restrict__ csr_src, float* __restrict__ csr_w, int e) {
    int i = blockIdx.x * blockDim.x + threadIdx.x;
    if (i < e) {
        int r = row[i], c = col[i];
        int p = atomicAdd(&cursor[c], 1);
        csr_src[p] = r;
        csr_w[p] = dis[r] * ew[i] * dis[c];
    }
}

// ---------------- gather ----------------
// POSTAFF (L2/L3/L4): out = sc*A + sh*(dis^2 + sum w)   [BN linear, hoisted out of loop]
// PREAFF  (L5): per-edge relu(sc*u+sh)                   [relu breaks linearity]
// EPI     (L1): out = relu(A + bias), channel stats into buckets
template <int D, int POSTAFF, int PREAFF, int EPI>
__global__ void k_gather(const float* __restrict__ src, const int* __restrict__ ptr,
                         const int* __restrict__ csr_src, const float* __restrict__ csr_w,
                         const float* __restrict__ dis,
                         const float* __restrict__ scale, const float* __restrict__ shift,
                         const float* __restrict__ bias, float* __restrict__ part,
                         float* __restrict__ out, int n) {
    const int TPN = D / 4;
    __shared__ float ls[EPI ? D : 1], lq[EPI ? D : 1];
    int tid = threadIdx.x;
    if (EPI) {
        if (tid < D) { ls[tid] = 0.f; lq[tid] = 0.f; }
        __syncthreads();
    }
    int t = blockIdx.x * blockDim.x + tid;
    int node = t / TPN;
    int l4 = t - node * TPN;
    bool valid = node < n;
    int nc = valid ? node : n - 1;

    float4 sc = {0,0,0,0}, sh = {0,0,0,0};
    if (POSTAFF || PREAFF) {
        sc = ((const float4*)scale)[l4];
        sh = ((const float4*)shift)[l4];
    }
    const float4* s4 = (const float4*)src;
    float d = dis[nc];
    float w0 = d * d;
    float4 v = s4[nc * TPN + l4];
    if (PREAFF) {
        v.x = fmaxf(sc.x * v.x + sh.x, 0.f); v.y = fmaxf(sc.y * v.y + sh.y, 0.f);
        v.z = fmaxf(sc.z * v.z + sh.z, 0.f); v.w = fmaxf(sc.w * v.w + sh.w, 0.f);
    }
    float4 acc = { w0 * v.x, w0 * v.y, w0 * v.z, w0 * v.w };
    float sumw = w0;
    int p0 = ptr[nc], p1 = ptr[nc + 1];
    int p = p0;
    for (; p + 4 <= p1; p += 4) {
        int s0 = csr_src[p], s1 = csr_src[p+1], s2 = csr_src[p+2], s3 = csr_src[p+3];
        float e0 = csr_w[p], e1 = csr_w[p+1], e2 = csr_w[p+2], e3 = csr_w[p+3];
        float4 u0 = s4[s0 * TPN + l4];
        float4 u1 = s4[s1 * TPN + l4];
        float4 u2 = s4[s2 * TPN + l4];
        float4 u3 = s4[s3 * TPN + l4];
        if (PREAFF) {
            u0.x = fmaxf(sc.x*u0.x+sh.x,0.f); u0.y = fmaxf(sc.y*u0.y+sh.y,0.f);
            u0.z = fmaxf(sc.z*u0.z+sh.z,0.f); u0.w = fmaxf(sc.w*u0.w+sh.w,0.f);
            u1.x = fmaxf(sc.x*u1.x+sh.x,0.f); u1.y = fmaxf(sc.y*u1.y+sh.y,0.f);
            u1.z = fmaxf(sc.z*u1.z+sh.z,0.f); u1.w = fmaxf(sc.w*u1.w+sh.w,0.f);
            u2.x = fmaxf(sc.x*u2.x+sh.x,0.f); u2.y = fmaxf(sc.y*u2.y+sh.y,0.f);
            u2.z = fmaxf(sc.z*u2.z+sh.z,0.f); u2.w = fmaxf(sc.w*u2.w+sh.w,0.f);
            u3.x = fmaxf(sc.x*u3.x+sh.x,0.f); u3.y = fmaxf(sc.y*u3.y+sh.y,0.f);
            u3.z = fmaxf(sc.z*u3.z+sh.z,0.f); u3.w = fmaxf(sc.w*u3.w+sh.w,0.f);
        }
        acc.x += e0*u0.x + e1*u1.x + e2*u2.x + e3*u3.x;
        acc.y += e0*u0.y + e1*u1.y + e2*u2.y + e3*u3.y;
        acc.z += e0*u0.z + e1*u1.z + e2*u2.z + e3*u3.z;
        acc.w += e0*u0.w + e1*u1.w + e2*u2.w + e3*u3.w;
        if (POSTAFF) sumw += e0 + e1 + e2 + e3;
    }
    for (; p < p1; ++p) {
        int s = csr_src[p];
        float w = csr_w[p];
        float4 u = s4[s * TPN + l4];
        if (PREAFF) {
            u.x = fmaxf(sc.x*u.x+sh.x,0.f); u.y = fmaxf(sc.y*u.y+sh.y,0.f);
            u.z = fmaxf(sc.z*u.z+sh.z,0.f); u.w = fmaxf(sc.w*u.w+sh.w,0.f);
        }
        acc.x += w*u.x; acc.y += w*u.y; acc.z += w*u.z; acc.w += w*u.w;
        if (POSTAFF) sumw += w;
    }
    if (POSTAFF) {
        acc.x = sc.x * acc.x + sh.x * sumw;
        acc.y = sc.y * acc.y + sh.y * sumw;
        acc.z = sc.z * acc.z + sh.z * sumw;
        acc.w = sc.w * acc.w + sh.w * sumw;
    }
    if (EPI) {
        float4 b = ((const float4*)bias)[l4];
        acc.x = fmaxf(acc.x + b.x, 0.f);
        acc.y = fmaxf(acc.y + b.y, 0.f);
        acc.z = fmaxf(acc.z + b.z, 0.f);
        acc.w = fmaxf(acc.w + b.w, 0.f);
        if (valid) ((float4*)out)[nc * TPN + l4] = acc;
        float s0 = valid ? acc.x : 0.f, s1 = valid ? acc.y : 0.f;
        float s2 = valid ? acc.z : 0.f, s3 = valid ? acc.w : 0.f;
        float q0 = s0*s0, q1 = s1*s1, q2 = s2*s2, q3 = s3*s3;
        for (int off = TPN; off < 64; off <<= 1) {
            s0 += __shfl_down(s0, off, 64); s1 += __shfl_down(s1, off, 64);
            s2 += __shfl_down(s2, off, 64); s3 += __shfl_down(s3, off, 64);
            q0 += __shfl_down(q0, off, 64); q1 += __shfl_down(q1, off, 64);
            q2 += __shfl_down(q2, off, 64); q3 += __shfl_down(q3, off, 64);
        }
        int lane = tid & 63;
        if (lane < TPN) {
            atomicAdd(&ls[4*lane+0], s0); atomicAdd(&ls[4*lane+1], s1);
            atomicAdd(&ls[4*lane+2], s2); atomicAdd(&ls[4*lane+3], s3);
            atomicAdd(&lq[4*lane+0], q0); atomicAdd(&lq[4*lane+1], q1);
            atomicAdd(&lq[4*lane+2], q2); atomicAdd(&lq[4*lane+3], q3);
        }
        __syncthreads();
        int bkt = (blockIdx.x & (NBUCKET - 1)) * 256;
        if (tid < D) {
            atomicAdd(&part[bkt + tid], ls[tid]);
            atomicAdd(&part[bkt + 128 + tid], lq[tid]);
        }
    } else {
        if (valid) ((float4*)out)[nc * TPN + l4] = acc;
    }
}

// ---------------- node-blocked GEMM: NPT nodes x 4 outputs per thread ----------------
template <int DIN, int DOUT, int RELU, int EPI, int NPT>
__global__ void k_gemm(const float* __restrict__ h, const float* __restrict__ W,
                       const float* __restrict__ bias, float* __restrict__ part,
                       float* __restrict__ m, int n) {
    const int TPN = DOUT / 4;
    const int GPB = 256 / TPN;
    __shared__ float Wl[DIN * DOUT];
    __shared__ float ls[EPI ? DOUT : 1], lq[EPI ? DOUT : 1];
    int tid = threadIdx.x;
    for (int i = tid; i < DIN * DOUT / 4; i += 256)
        ((float4*)Wl)[i] = ((const float4*)W)[i];
    if (EPI && tid < DOUT) { ls[tid] = 0.f; lq[tid] = 0.f; }
    __syncthreads();

    int jq = tid % TPN;
    int group = tid / TPN;
    int node0 = (blockIdx.x * GPB + group) * NPT;
    const float4* h4 = (const float4*)h;
    int hb[NPT];
    bool val[NPT];
#pragma unroll
    for (int i = 0; i < NPT; ++i) {
        int nd = node0 + i;
        val[i] = nd < n;
        hb[i] = (val[i] ? nd : n - 1) * (DIN / 4);
    }
    float4 acc[NPT];
#pragma unroll
    for (int i = 0; i < NPT; ++i) acc[i] = {0.f, 0.f, 0.f, 0.f};

#pragma unroll 4
    for (int k4 = 0; k4 < DIN / 4; ++k4) {
        const float* wb = &Wl[(k4 * 4) * DOUT + jq * 4];
        float4 w0 = *(const float4*)(wb);
        float4 w1 = *(const float4*)(wb + DOUT);
        float4 w2 = *(const float4*)(wb + 2 * DOUT);
        float4 w3 = *(const float4*)(wb + 3 * DOUT);
#pragma unroll
        for (int i = 0; i < NPT; ++i) {
            float4 hv = h4[hb[i] + k4];
            acc[i].x += hv.x*w0.x + hv.y*w1.x + hv.z*w2.x + hv.w*w3.x;
            acc[i].y += hv.x*w0.y + hv.y*w1.y + hv.z*w2.y + hv.w*w3.y;
            acc[i].z += hv.x*w0.z + hv.y*w1.z + hv.z*w2.z + hv.w*w3.z;
            acc[i].w += hv.x*w0.w + hv.y*w1.w + hv.z*w2.w + hv.w*w3.w;
        }
    }

    float4 bv = {0,0,0,0};
    if (EPI) bv = ((const float4*)bias)[jq];
    float4 sv = {0,0,0,0}, qv = {0,0,0,0};
#pragma unroll
    for (int i = 0; i < NPT; ++i) {
        float4 a = acc[i];
        if (EPI) {
            a.x += bv.x; a.y += bv.y; a.z += bv.z; a.w += bv.w;
            if (RELU) {
                a.x = fmaxf(a.x, 0.f); a.y = fmaxf(a.y, 0.f);
                a.z = fmaxf(a.z, 0.f); a.w = fmaxf(a.w, 0.f);
            }
        }
        if (val[i]) {
            ((float4*)m)[(node0 + i) * TPN + jq] = a;
            if (EPI) {
                sv.x += a.x; sv.y += a.y; sv.z += a.z; sv.w += a.w;
                qv.x += a.x*a.x; qv.y += a.y*a.y; qv.z += a.z*a.z; qv.w += a.w*a.w;
            }
        }
    }
    if (EPI) {
        for (int off = TPN; off < 64; off <<= 1) {
            sv.x += __shfl_down(sv.x, off, 64); sv.y += __shfl_down(sv.y, off, 64);
            sv.z += __shfl_down(sv.z, off, 64); sv.w += __shfl_down(sv.w, off, 64);
            qv.x += __shfl_down(qv.x, off, 64); qv.y += __shfl_down(qv.y, off, 64);
            qv.z += __shfl_down(qv.z, off, 64); qv.w += __shfl_down(qv.w, off, 64);
        }
        int lane = tid & 63;
        if (lane < TPN) {
            atomicAdd(&ls[4*lane+0], sv.x); atomicAdd(&ls[4*lane+1], sv.y);
            atomicAdd(&ls[4*lane+2], sv.z); atomicAdd(&ls[4*lane+3], sv.w);
            atomicAdd(&lq[4*lane+0], qv.x); atomicAdd(&lq[4*lane+1], qv.y);
            atomicAdd(&lq[4*lane+2], qv.z); atomicAdd(&lq[4*lane+3], qv.w);
        }
        __syncthreads();
        int bkt = (blockIdx.x & (NBUCKET - 1)) * 256;
        if (tid < DOUT) {
            atomicAdd(&part[bkt + tid], ls[tid]);
            atomicAdd(&part[bkt + 128 + tid], lq[tid]);
        }
    }
}

// ---------------- BN finalize (self-zeroing buckets) ----------------
__global__ void k_finalize(float* part, const float* __restrict__ g, const float* __restrict__ bt,
                           float* scale, float* shift, int dout, int n) {
    int j = threadIdx.x;
    if (j >= dout) return;
    float s = 0.f, q = 0.f;
    for (int b = 0; b < NBUCKET; ++b) {
        s += part[b * 256 + j];       part[b * 256 + j] = 0.f;
        q += part[b * 256 + 128 + j]; part[b * 256 + 128 + j] = 0.f;
    }
    float mu = s / n;
    float var = q / n - mu * mu;
    float a = g[j] * rsqrtf(var + 1e-5f);
    scale[j] = a;
    shift[j] = bt[j] - mu * a;
}

// ---------------- fused pool (BN5 inline) + MLP head, atomic-free ----------------
__global__ void k_poolhead(const float* __restrict__ h, const int* __restrict__ batch,
                           const float* __restrict__ scale, const float* __restrict__ shift,
                           const float* __restrict__ fc1w, const float* __restrict__ fc1b,
                           const float* __restrict__ fc2w, const float* __restrict__ fc2b,
                           float* __restrict__ out, int n) {
    __shared__ float tmp[256];
    __shared__ float pl[128];
    int g = blockIdx.x;
    int tid = threadIdx.x;
    int j = tid & 127, part = tid >> 7;
    // lower_bound(batch, g) and lower_bound(batch, g+1); batch is sorted
    int a = 0, b = n;
    while (a < b) { int mid = (a + b) >> 1; if (batch[mid] < g) a = mid + 1; else b = mid; }
    int lo = a;
    b = n;
    while (a < b) { int mid = (a + b) >> 1; if (batch[mid] < g + 1) a = mid + 1; else b = mid; }
    int hi = a;

    float acc = 0.f;
    for (int node = lo + part; node < hi; node += 2) acc += h[(long)node * 128 + j];
    tmp[tid] = acc;
    __syncthreads();
    if (tid < 128) {
        float cnt = (float)(hi - lo);
        // sum of BN'd values = scale*sum + shift*count; then relu (post-pool)
        float p = scale[tid] * (tmp[tid] + tmp[tid + 128]) + shift[tid] * cnt;
        pl[tid] = fmaxf(p, 0.f);
    }
    __syncthreads();
    if (tid < 64) {
        float v1 = fc1b[tid];
        for (int k = 0; k < 128; ++k) v1 += pl[k] * fc1w[k * 64 + tid];
        v1 = fmaxf(v1, 0.f);
        float v = v1 * fc2w[tid];
        for (int off = 32; off > 0; off >>= 1) v += __shfl_down(v, off, 64);
        if (tid == 0) out[g] = v + fc2b[0];
    }
}

// ---------------- driver ----------------
extern "C" void kernel_launch(void* const* d_in, const int* in_sizes, int n_in,
                              void* d_out, int out_size, void* d_ws, size_t ws_size,
                              hipStream_t stream) {
    const float* x     = (const float*)d_in[0];
    const int*   ei    = (const int*)d_in[1];
    const float* ew    = (const float*)d_in[2];
    const int*   batch = (const int*)d_in[3];
    const float *W[5], *b[5], *gm[5], *bt[5];
    for (int i = 0; i < 5; ++i) {
        W[i]  = (const float*)d_in[4 + 4 * i];
        b[i]  = (const float*)d_in[5 + 4 * i];
        gm[i] = (const float*)d_in[6 + 4 * i];
        bt[i] = (const float*)d_in[7 + 4 * i];
    }
    const float* fc1w = (const float*)d_in[24];
    const float* fc1b = (const float*)d_in[25];
    const float* fc2w = (const float*)d_in[26];
    const float* fc2b = (const float*)d_in[27];
    float* out = (float*)d_out;

    // workspace layout
    char* wsb = (char*)d_ws;
    float* dis    = (float*)wsb;  wsb += sizeof(float) * NN;
    int*   ptr    = (int*)wsb;    wsb += sizeof(int) * (NN + 1);
    int*   cursor = (int*)wsb;    wsb += sizeof(int) * NN;
    int*   bsum   = (int*)wsb;    wsb += sizeof(int) * 256;
    int*   csr_src= (int*)wsb;    wsb += sizeof(int) * NE;
    float* csr_w  = (float*)wsb;  wsb += sizeof(float) * NE;
    float* part   = (float*)wsb;  wsb += sizeof(float) * NBUCKET * 256;
    float* scl    = (float*)wsb;  wsb += sizeof(float) * 5 * 128;
    float* shf    = (float*)wsb;  wsb += sizeof(float) * 5 * 128;
    float* buf1   = (float*)wsb;  wsb += sizeof(float) * (long)NN * 128;
    float* buf2   = (float*)wsb;  wsb += sizeof(float) * (long)NN * 128;

    const int* row = ei;
    const int* col = ei + NE;
    const int B = 256;
    const int NB_N = (NN + B - 1) / B;   // 196
    const int NB_E = (NE + B - 1) / B;

    // prologue: gcn_norm + CSR build (8 launches)
    k_init<<<NB_N, B, 0, stream>>>(dis, cursor, part, NN);
    k_edge<<<NB_E, B, 0, stream>>>(col, ew, dis, cursor, NE);
    k_dis<<<NB_N, B, 0, stream>>>(dis, NN);
    k_scan1<<<NB_N, B, 0, stream>>>(cursor, ptr, bsum, NN);
    k_scan2<<<1, 256, 0, stream>>>(bsum, NB_N);
    k_scan3<<<NB_N, B, 0, stream>>>(ptr, bsum, NN, NE);
    k_copy_int<<<NB_N, B, 0, stream>>>(ptr, cursor, NN);
    k_fill<<<NB_E, B, 0, stream>>>(row, col, ew, dis, cursor, csr_src, csr_w, NE);

    auto grid4 = [](long threads) { return (int)((threads + 255) / 256); };
    auto ggrid = [](int npb) { return (NN + npb - 1) / npb; };

    // L1: gemm 128->16 (NPT=2), gather16 + bias+relu+stats
    k_gemm<128, 16, 0, 0, 2><<<ggrid((256/4)*2), B, 0, stream>>>(x, W[0], b[0], part, buf1, NN);
    k_gather<16, 0, 0, 1><<<grid4((long)NN * 4), B, 0, stream>>>(buf1, ptr, csr_src, csr_w, dis,
                                                                 nullptr, nullptr, b[0], part, buf2, NN);
    k_finalize<<<1, 128, 0, stream>>>(part, gm[0], bt[0], scl + 0, shf + 0, 16, NN);

    // L2: gather16 (BN1 hoisted), gemm 16->32 + bias+relu+stats
    k_gather<16, 1, 0, 0><<<grid4((long)NN * 4), B, 0, stream>>>(buf2, ptr, csr_src, csr_w, dis,
                                                                 scl + 0, shf + 0, nullptr, nullptr, buf1, NN);
    k_gemm<16, 32, 1, 1, 4><<<ggrid((256/8)*4), B, 0, stream>>>(buf1, W[1], b[1], part, buf2, NN);
    k_finalize<<<1, 128, 0, stream>>>(part, gm[1], bt[1], scl + 128, shf + 128, 32, NN);

    // L3: gather32 (BN2 hoisted), gemm 32->64 + bias+relu+stats
    k_gather<32, 1, 0, 0><<<grid4((long)NN * 8), B, 0, stream>>>(buf2, ptr, csr_src, csr_w, dis,
                                                                 scl + 128, shf + 128, nullptr, nullptr, buf1, NN);
    k_gemm<32, 64, 1, 1, 4><<<ggrid((256/16)*4), B, 0, stream>>>(buf1, W[2], b[2], part, buf2, NN);
    k_finalize<<<1, 128, 0, stream>>>(part, gm[2], bt[2], scl + 256, shf + 256, 64, NN);

    // L4: gather64 (BN3 hoisted), gemm 64->64 + bias+stats (relu post-BN)
    k_gather<64, 1, 0, 0><<<grid4((long)NN * 16), B, 0, stream>>>(buf2, ptr, csr_src, csr_w, dis,
                                                                  scl + 256, shf + 256, nullptr, nullptr, buf1, NN);
    k_gemm<64, 64, 0, 1, 4><<<ggrid((256/16)*4), B, 0, stream>>>(buf1, W[3], b[3], part, buf2, NN);
    k_finalize<<<1, 128, 0, stream>>>(part, gm[3], bt[3], scl + 384, shf + 384, 64, NN);

    // L5: gather64 (BN4 + relu per-edge), gemm 64->128 + bias+stats
    k_gather<64, 0, 1, 0><<<grid4((long)NN * 16), B, 0, stream>>>(buf2, ptr, csr_src, csr_w, dis,
                                                                  scl + 384, shf + 384, nullptr, nullptr, buf1, NN);
    k_gemm<64, 128, 0, 1, 4><<<ggrid((256/32)*4), B, 0, stream>>>(buf1, W[4], b[4], part, buf2, NN);
    k_finalize<<<1, 128, 0, stream>>>(part, gm[4], bt[4], scl + 512, shf + 512, 128, NN);

    // fused pool (BN5) + head
    k_poolhead<<<NG, 256, 0, stream>>>(buf2, batch, scl + 512, shf + 512,
                                       fc1w, fc1b, fc2w, fc2b, out, NN);
}